// Round 6
// baseline (8224.175 us; speedup 1.0000x reference)
//
#include <hip/hip_runtime.h>

typedef __bf16 bf16;
typedef __bf16 bf16x8 __attribute__((ext_vector_type(8)));
typedef __bf16 bf16x4 __attribute__((ext_vector_type(4)));
typedef float f32x4 __attribute__((ext_vector_type(4)));

#define GLL16(gp, lp)                                                          \
  __builtin_amdgcn_global_load_lds(                                            \
      (const __attribute__((address_space(1))) unsigned int*)(gp),             \
      (__attribute__((address_space(3))) unsigned int*)(lp), 16, 0, 0)

// ------------------------------------------------------- fused fp32->bf16 casts
__global__ __launch_bounds__(256) void cast3_f32_bf16(
    const float* __restrict__ a, bf16* __restrict__ oa, int na4,
    const float* __restrict__ b, bf16* __restrict__ ob, int nb4,
    const float* __restrict__ c, bf16* __restrict__ oc, int nc4) {
  int i = blockIdx.x * blockDim.x + threadIdx.x;
  int stride = gridDim.x * blockDim.x;
  int total = na4 + nb4 + nc4;
  for (; i < total; i += stride) {
    const float4* src;
    bf16x4* dst;
    int j = i;
    if (j < na4) {
      src = (const float4*)a + j; dst = (bf16x4*)oa + j;
    } else if ((j -= na4) < nb4) {
      src = (const float4*)b + j; dst = (bf16x4*)ob + j;
    } else {
      j -= nb4;
      src = (const float4*)c + j; dst = (bf16x4*)oc + j;
    }
    float4 v = *src;
    bf16x4 o;
    o[0] = (bf16)v.x; o[1] = (bf16)v.y; o[2] = (bf16)v.z; o[3] = (bf16)v.w;
    *dst = o;
  }
}

// ---------------------------------------------------------------- GEMM C = A * B^T
template <int K, int LDC, typename CT>
__global__ __launch_bounds__(256) void gemm_bt(
    const bf16* __restrict__ A, const bf16* __restrict__ B,
    CT* __restrict__ C) {
  __shared__ __align__(16) bf16 As[128 * 64];
  __shared__ __align__(16) bf16 Bs[128 * 64];
  const int tid  = threadIdx.x;
  const int lane = tid & 63;
  const int wave = tid >> 6;
  const int ln15 = lane & 15, quad = lane >> 4;
  const int wm = wave >> 1, wn = wave & 1;
  const int m0 = blockIdx.y * 128, n0 = blockIdx.x * 128;

  f32x4 acc[4][4] = {};

  for (int k0 = 0; k0 < K; k0 += 64) {
    __syncthreads();
#pragma unroll
    for (int j = 0; j < 4; ++j) {
      int gbase = j * 256 + wave * 64;
      int g = gbase + lane;
      int r = g >> 3, c = (g & 7) ^ (r & 7);
      GLL16(A + (size_t)(m0 + r) * K + k0 + c * 8, As + (size_t)gbase * 8);
    }
#pragma unroll
    for (int j = 0; j < 4; ++j) {
      int gbase = j * 256 + wave * 64;
      int g = gbase + lane;
      int r = g >> 3, c = (g & 7) ^ (r & 7);
      GLL16(B + (size_t)(n0 + r) * K + k0 + c * 8, Bs + (size_t)gbase * 8);
    }
    __syncthreads();
#pragma unroll
    for (int kk = 0; kk < 2; ++kk) {
      bf16x8 af[4], bfr[4];
#pragma unroll
      for (int mi = 0; mi < 4; ++mi) {
        int m = wm * 64 + mi * 16 + ln15;
        int cg = kk * 4 + quad;
        af[mi] = *(const bf16x8*)(As + (m * 8 + (cg ^ (m & 7))) * 8);
      }
#pragma unroll
      for (int ni = 0; ni < 4; ++ni) {
        int n = wn * 64 + ni * 16 + ln15;
        int cg = kk * 4 + quad;
        bfr[ni] = *(const bf16x8*)(Bs + (n * 8 + (cg ^ (n & 7))) * 8);
      }
#pragma unroll
      for (int mi = 0; mi < 4; ++mi)
#pragma unroll
        for (int ni = 0; ni < 4; ++ni)
          acc[mi][ni] = __builtin_amdgcn_mfma_f32_16x16x32_bf16(
              af[mi], bfr[ni], acc[mi][ni], 0, 0, 0);
    }
  }
#pragma unroll
  for (int mi = 0; mi < 4; ++mi)
#pragma unroll
    for (int ni = 0; ni < 4; ++ni)
#pragma unroll
      for (int r = 0; r < 4; ++r) {
        int row = m0 + wm * 64 + mi * 16 + quad * 4 + r;
        int col = n0 + wn * 64 + ni * 16 + ln15;
        C[(size_t)row * LDC + col] = (CT)acc[mi][ni][r];
      }
}

// ---------------------------------------------------------------- qkv epilogue
__global__ __launch_bounds__(256) void qkv_post(
    const bf16* __restrict__ qkv, const float* __restrict__ ve,
    const float* __restrict__ lambdas, bf16* __restrict__ qn,
    bf16* __restrict__ kn, bf16* __restrict__ vt) {
  const int h  = blockIdx.x;
  const int t0 = blockIdx.y * 64;
  const int tid = threadIdx.x;
  const int wave = tid >> 6, lane = tid & 63;
  __shared__ __align__(16) float tile[64][129];

  const int j = lane;
  float cth = 1.0f, sth = 0.0f;
  for (int i = 0; i < 16; ++i) {
    int t = t0 + wave * 16 + i;
    if (j < 32) {
      float ang = exp2f((float)j * (-10.0f / 31.0f));
      float th = (float)t * ang;
      __sincosf(th, &sth, &cth);
    }
#pragma unroll
    for (int qk = 0; qk < 2; ++qk) {
      const bf16* row = qkv + (size_t)t * 3072 + qk * 1024 + h * 128;
      float x1 = (float)row[j], x2 = (float)row[j + 64];
      float ss = x1 * x1 + x2 * x2;
#pragma unroll
      for (int m = 1; m < 64; m <<= 1) ss += __shfl_xor(ss, m, 64);
      float rinv = rsqrtf(ss * (1.0f / 128.0f) + 1.1920929e-7f);
      if (qk == 0) rinv *= 0.12f;  // fold ATTN_SCALE into q
      float y1 = (x1 * cth + x2 * sth) * rinv;
      float y2 = (x2 * cth - x1 * sth) * rinv;
      bf16* orow = (qk == 0 ? qn : kn) + (size_t)t * 1024 + h * 128;
      orow[j] = (bf16)y1;
      orow[j + 64] = (bf16)y2;
    }
  }

  float l0 = lambdas[0], l1 = lambdas[1];
  for (int c = 0; c < 32; ++c) {
    int idx = c * 256 + tid;
    int d = idx & 127, tl = idx >> 7;
    int t = t0 + tl;
    float v = (float)qkv[(size_t)t * 3072 + 2048 + h * 128 + d];
    float vev = ve[(size_t)t * 1024 + h * 128 + d];
    tile[tl][d] = l0 * v + l1 * vev;
  }
  __syncthreads();
  for (int c = 0; c < 32; ++c) {
    int idx = c * 256 + tid;
    int tl = idx & 63, d = idx >> 6;
    vt[((size_t)(h * 128 + d)) * 4096 + t0 + tl] = (bf16)tile[tl][d];
  }
}

// ---------------------------------------------------------------- flash attention
// Round 6: K/V go DIRECTLY from global to registers (disjoint per-wave slices,
// zero duplication, register ping-pong prefetched one iter ahead) — no K/V LDS
// staging, no GLL16, no staging barrier. LDS holds only the P [64q][64kv]
// round-trip, double-buffered -> exactly ONE barrier per kv-iter.
//  phase 1: wave w computes S^T[kv=w*16..+15][all 64 q] (K A-frags, 4x b128-equiv)
//  phase 2: wave w computes O^T[d=w*32..+31][all 64 q]  (V A-frags + P B-frags)
// Raw-exp softmax (|S| <= 0.12*128), deferred l, one LDS exchange at the end.
__global__ __launch_bounds__(256, 2) void flash_attn(
    const bf16* __restrict__ qn, const bf16* __restrict__ kn,
    const bf16* __restrict__ vt, bf16* __restrict__ y) {
  const int halfg = blockIdx.x >> 8;
  const int idx = blockIdx.x & 255;
  const int h = idx & 7;
  const int p = idx >> 3;
  const int qtile = halfg ? p : 63 - p;
  const int tid = threadIdx.x;
  const int wave = tid >> 6, lane = tid & 63;
  const int ln15 = lane & 15, quad = lane >> 4;
  const int ln7 = ln15 & 7;

  __shared__ __align__(16) bf16 P[2][64 * 64];  // [buf][q][8 gran], ^ (q&7)
  __shared__ float rsb[4][64];

  const int q0 = qtile * 64;
  const int nkv = qtile + 1;

  // Q B-frags for all 4 n-tiles (B[k=d][n=q]); resident all iters (64 VGPR).
  bf16x8 qf[4][4];
#pragma unroll
  for (int nf = 0; nf < 4; ++nf) {
    const bf16* qb = qn + (size_t)(q0 + nf * 16 + ln15) * 1024 + h * 128 + quad * 8;
#pragma unroll
    for (int ks = 0; ks < 4; ++ks) qf[nf][ks] = *(const bf16x8*)(qb + ks * 32);
  }

  // Per-wave K slice (16 kv x 128 d) and V slice (32 d x 64 kv) base pointers.
  const bf16* kbase = kn + (size_t)(wave * 16 + ln15) * 1024 + h * 128 + quad * 8;
  const bf16* vbase =
      vt + ((size_t)(h * 128 + wave * 32 + ln15)) * 4096 + quad * 8;

  bf16x8 kf[2][4];    // [buf][ks]   A-frags: m=kv(ln15), k=d(ks*32+quad*8)
  bf16x8 vf[2][2][2]; // [buf][mf][ks2] A-frags: m=d, k=kv(ks2*32+quad*8)

  auto loadK = [&](int kt, int buf) {
    const size_t off = (size_t)(kt * 64) * 1024;
#pragma unroll
    for (int ks = 0; ks < 4; ++ks)
      kf[buf][ks] = *(const bf16x8*)(kbase + off + ks * 32);
  };
  auto loadV = [&](int kt, int buf) {
    const int kv0 = kt * 64;
#pragma unroll
    for (int mf = 0; mf < 2; ++mf)
#pragma unroll
      for (int ks2 = 0; ks2 < 2; ++ks2)
        vf[buf][mf][ks2] =
            *(const bf16x8*)(vbase + (size_t)(mf * 16) * 4096 + kv0 + ks2 * 32);
  };

  f32x4 acc_o[2][4] = {};
  float rs[4] = {0.f, 0.f, 0.f, 0.f};

  loadK(0, 0);
  loadV(0, 0);

  for (int kt = 0; kt < nkv; ++kt) {
    const int cur = kt & 1, nxt = cur ^ 1;
    const int kv0 = kt * 64;
    const int ktn = (kt + 1 < nkv) ? kt + 1 : kt;  // clamped prefetch

    // ---- phase 1: S^T[kv-slice][all q] = K-slice * Q^T
    f32x4 accs[4] = {};
#pragma unroll
    for (int ks = 0; ks < 4; ++ks)
#pragma unroll
      for (int nf = 0; nf < 4; ++nf)
        accs[nf] = __builtin_amdgcn_mfma_f32_16x16x32_bf16(
            kf[cur][ks], qf[nf][ks], accs[nf], 0, 0, 0);

    loadK(ktn, nxt);  // prefetch next K slice (lands during exp+phase2)

    // exp + causal mask + packed P store (4 consecutive kv at fixed q).
    const bool diag = (kt == nkv - 1);
    const int kvbase = kv0 + wave * 16 + quad * 4;
#pragma unroll
    for (int nf = 0; nf < 4; ++nf) {
      const int q = q0 + nf * 16 + ln15;
      bf16x4 pk;
#pragma unroll
      for (int r = 0; r < 4; ++r) {
        float pe = __expf(accs[nf][r]);
        if (diag && kvbase + r > q) pe = 0.f;
        rs[nf] += pe;
        pk[r] = (bf16)pe;
      }
      int gp = (wave * 2 + (quad >> 1)) ^ ln7;
      *(bf16x4*)(&P[cur][0] + ((nf * 16 + ln15) * 8 + gp) * 8 + 4 * (quad & 1)) = pk;
    }
    __syncthreads();  // P[cur] complete; P[cur] reuse at kt+2 gated by kt+1's barrier

    // ---- phase 2: O^T[d-slice][all q] += V^T-slice * P^T
#pragma unroll
    for (int ks2 = 0; ks2 < 2; ++ks2) {
      bf16x8 pf[4];
#pragma unroll
      for (int nf = 0; nf < 4; ++nf)
        pf[nf] = *(const bf16x8*)(
            &P[cur][0] + ((nf * 16 + ln15) * 8 + ((ks2 * 4 + quad) ^ ln7)) * 8);
#pragma unroll
      for (int mf = 0; mf < 2; ++mf)
#pragma unroll
        for (int nf = 0; nf < 4; ++nf)
          acc_o[mf][nf] = __builtin_amdgcn_mfma_f32_16x16x32_bf16(
              vf[cur][mf][ks2], pf[nf], acc_o[mf][nf], 0, 0, 0);
    }

    loadV(ktn, nxt);  // prefetch next V slice (lands during next phase 1)
  }

  // l(q): reduce per-lane partials over quads, then across waves via LDS.
#pragma unroll
  for (int nf = 0; nf < 4; ++nf) {
    rs[nf] += __shfl_xor(rs[nf], 16, 64);
    rs[nf] += __shfl_xor(rs[nf], 32, 64);
  }
  if (lane < 16) {
#pragma unroll
    for (int nf = 0; nf < 4; ++nf) rsb[wave][nf * 16 + ln15] = rs[nf];
  }
  __syncthreads();
  float inv[4];
#pragma unroll
  for (int nf = 0; nf < 4; ++nf)
    inv[nf] = 1.0f / (rsb[0][nf * 16 + ln15] + rsb[1][nf * 16 + ln15] +
                      rsb[2][nf * 16 + ln15] + rsb[3][nf * 16 + ln15]);

  // O^T C-layout: d = w*32 + mf*16 + quad*4 + r, q = nf*16 + ln15.
#pragma unroll
  for (int mf = 0; mf < 2; ++mf)
#pragma unroll
    for (int nf = 0; nf < 4; ++nf) {
      bf16x4 o;
#pragma unroll
      for (int r = 0; r < 4; ++r) o[r] = (bf16)(acc_o[mf][nf][r] * inv[nf]);
      *(bf16x4*)(y + (size_t)(q0 + nf * 16 + ln15) * 1024 + h * 128 +
                 wave * 32 + mf * 16 + quad * 4) = o;
    }
}

// ---------------------------------------------------------------- launch
extern "C" void kernel_launch(void* const* d_in, const int* in_sizes, int n_in,
                              void* d_out, int out_size, void* d_ws,
                              size_t ws_size, hipStream_t stream) {
  const float* x       = (const float*)d_in[0];  // [1,4096,1024]
  const float* ve      = (const float*)d_in[1];  // [1,4096,1024]
  const float* qkv_w   = (const float*)d_in[2];  // [3,1024,1024]
  const float* lambdas = (const float*)d_in[3];  // [2]
  const float* c_proj  = (const float*)d_in[4];  // [1024,1024]
  float* out = (float*)d_out;                    // [1,4096,1024] fp32

  char* ws = (char*)d_ws;
  bf16* qkv   = (bf16*)ws;                    // 24 MiB
  bf16* xbf   = (bf16*)(ws + 25165824);       // 8 MiB
  bf16* wqkv  = (bf16*)(ws + 33554432);       // 6 MiB
  bf16* wproj = (bf16*)(ws + 39845888);       // 2 MiB
  bf16* qn    = (bf16*)(ws + 41943040);       // 8 MiB
  bf16* kn    = (bf16*)(ws + 50331648);       // 8 MiB
  bf16* vt    = (bf16*)(ws + 58720256);       // 8 MiB  [H][128][T]
  bf16* yb    = (bf16*)(ws + 67108864);       // 8 MiB

  cast3_f32_bf16<<<2048, 256, 0, stream>>>(x, xbf, 4194304 / 4, qkv_w, wqkv,
                                           3145728 / 4, c_proj, wproj,
                                           1048576 / 4);

  gemm_bt<1024, 3072, bf16><<<dim3(24, 32), 256, 0, stream>>>(xbf, wqkv, qkv);

  qkv_post<<<dim3(8, 64), 256, 0, stream>>>(qkv, ve, lambdas, qn, kn, vt);

  flash_attn<<<512, 256, 0, stream>>>(qn, kn, vt, yb);

  gemm_bt<1024, 1024, float><<<dim3(8, 32), 256, 0, stream>>>(yb, wproj, out);
}

// Round 7
// 261.115 us; speedup vs baseline: 31.4964x; 31.4964x over previous
//
#include <hip/hip_runtime.h>

typedef __bf16 bf16;
typedef __bf16 bf16x8 __attribute__((ext_vector_type(8)));
typedef __bf16 bf16x4 __attribute__((ext_vector_type(4)));
typedef float f32x4 __attribute__((ext_vector_type(4)));

#define GLL16(gp, lp)                                                          \
  __builtin_amdgcn_global_load_lds(                                            \
      (const __attribute__((address_space(1))) unsigned int*)(gp),             \
      (__attribute__((address_space(3))) unsigned int*)(lp), 16, 0, 0)

// ------------------------------------------------------- fused fp32->bf16 casts
__global__ __launch_bounds__(256) void cast3_f32_bf16(
    const float* __restrict__ a, bf16* __restrict__ oa, int na4,
    const float* __restrict__ b, bf16* __restrict__ ob, int nb4,
    const float* __restrict__ c, bf16* __restrict__ oc, int nc4) {
  int i = blockIdx.x * blockDim.x + threadIdx.x;
  int stride = gridDim.x * blockDim.x;
  int total = na4 + nb4 + nc4;
  for (; i < total; i += stride) {
    const float4* src;
    bf16x4* dst;
    int j = i;
    if (j < na4) {
      src = (const float4*)a + j; dst = (bf16x4*)oa + j;
    } else if ((j -= na4) < nb4) {
      src = (const float4*)b + j; dst = (bf16x4*)ob + j;
    } else {
      j -= nb4;
      src = (const float4*)c + j; dst = (bf16x4*)oc + j;
    }
    float4 v = *src;
    bf16x4 o;
    o[0] = (bf16)v.x; o[1] = (bf16)v.y; o[2] = (bf16)v.z; o[3] = (bf16)v.w;
    *dst = o;
  }
}

// ---------------------------------------------------------------- GEMM C = A * B^T
template <int K, int LDC, typename CT>
__global__ __launch_bounds__(256) void gemm_bt(
    const bf16* __restrict__ A, const bf16* __restrict__ B,
    CT* __restrict__ C) {
  __shared__ __align__(16) bf16 As[128 * 64];
  __shared__ __align__(16) bf16 Bs[128 * 64];
  const int tid  = threadIdx.x;
  const int lane = tid & 63;
  const int wave = tid >> 6;
  const int ln15 = lane & 15, quad = lane >> 4;
  const int wm = wave >> 1, wn = wave & 1;
  const int m0 = blockIdx.y * 128, n0 = blockIdx.x * 128;

  f32x4 acc[4][4] = {};

  for (int k0 = 0; k0 < K; k0 += 64) {
    __syncthreads();
#pragma unroll
    for (int j = 0; j < 4; ++j) {
      int gbase = j * 256 + wave * 64;
      int g = gbase + lane;
      int r = g >> 3, c = (g & 7) ^ (r & 7);
      GLL16(A + (size_t)(m0 + r) * K + k0 + c * 8, As + (size_t)gbase * 8);
    }
#pragma unroll
    for (int j = 0; j < 4; ++j) {
      int gbase = j * 256 + wave * 64;
      int g = gbase + lane;
      int r = g >> 3, c = (g & 7) ^ (r & 7);
      GLL16(B + (size_t)(n0 + r) * K + k0 + c * 8, Bs + (size_t)gbase * 8);
    }
    __syncthreads();
#pragma unroll
    for (int kk = 0; kk < 2; ++kk) {
      bf16x8 af[4], bfr[4];
#pragma unroll
      for (int mi = 0; mi < 4; ++mi) {
        int m = wm * 64 + mi * 16 + ln15;
        int cg = kk * 4 + quad;
        af[mi] = *(const bf16x8*)(As + (m * 8 + (cg ^ (m & 7))) * 8);
      }
#pragma unroll
      for (int ni = 0; ni < 4; ++ni) {
        int n = wn * 64 + ni * 16 + ln15;
        int cg = kk * 4 + quad;
        bfr[ni] = *(const bf16x8*)(Bs + (n * 8 + (cg ^ (n & 7))) * 8);
      }
#pragma unroll
      for (int mi = 0; mi < 4; ++mi)
#pragma unroll
        for (int ni = 0; ni < 4; ++ni)
          acc[mi][ni] = __builtin_amdgcn_mfma_f32_16x16x32_bf16(
              af[mi], bfr[ni], acc[mi][ni], 0, 0, 0);
    }
  }
#pragma unroll
  for (int mi = 0; mi < 4; ++mi)
#pragma unroll
    for (int ni = 0; ni < 4; ++ni)
#pragma unroll
      for (int r = 0; r < 4; ++r) {
        int row = m0 + wm * 64 + mi * 16 + quad * 4 + r;
        int col = n0 + wn * 64 + ni * 16 + ln15;
        C[(size_t)row * LDC + col] = (CT)acc[mi][ni][r];
      }
}

// ---------------------------------------------------------------- qkv epilogue
__global__ __launch_bounds__(256) void qkv_post(
    const bf16* __restrict__ qkv, const float* __restrict__ ve,
    const float* __restrict__ lambdas, bf16* __restrict__ qn,
    bf16* __restrict__ kn, bf16* __restrict__ vt) {
  const int h  = blockIdx.x;
  const int t0 = blockIdx.y * 64;
  const int tid = threadIdx.x;
  const int wave = tid >> 6, lane = tid & 63;
  __shared__ __align__(16) float tile[64][129];

  const int j = lane;
  float cth = 1.0f, sth = 0.0f;
  for (int i = 0; i < 16; ++i) {
    int t = t0 + wave * 16 + i;
    if (j < 32) {
      float ang = exp2f((float)j * (-10.0f / 31.0f));
      float th = (float)t * ang;
      __sincosf(th, &sth, &cth);
    }
#pragma unroll
    for (int qk = 0; qk < 2; ++qk) {
      const bf16* row = qkv + (size_t)t * 3072 + qk * 1024 + h * 128;
      float x1 = (float)row[j], x2 = (float)row[j + 64];
      float ss = x1 * x1 + x2 * x2;
#pragma unroll
      for (int m = 1; m < 64; m <<= 1) ss += __shfl_xor(ss, m, 64);
      float rinv = rsqrtf(ss * (1.0f / 128.0f) + 1.1920929e-7f);
      if (qk == 0) rinv *= 0.12f;  // fold ATTN_SCALE into q
      float y1 = (x1 * cth + x2 * sth) * rinv;
      float y2 = (x2 * cth - x1 * sth) * rinv;
      bf16* orow = (qk == 0 ? qn : kn) + (size_t)t * 1024 + h * 128;
      orow[j] = (bf16)y1;
      orow[j + 64] = (bf16)y2;
    }
  }

  float l0 = lambdas[0], l1 = lambdas[1];
  for (int c = 0; c < 32; ++c) {
    int idx = c * 256 + tid;
    int d = idx & 127, tl = idx >> 7;
    int t = t0 + tl;
    float v = (float)qkv[(size_t)t * 3072 + 2048 + h * 128 + d];
    float vev = ve[(size_t)t * 1024 + h * 128 + d];
    tile[tl][d] = l0 * v + l1 * vev;
  }
  __syncthreads();
  for (int c = 0; c < 32; ++c) {
    int idx = c * 256 + tid;
    int tl = idx & 63, d = idx >> 6;
    vt[((size_t)(h * 128 + d)) * 4096 + t0 + tl] = (bf16)tile[tl][d];
  }
}

// ---------------------------------------------------------------- flash attention
// Round 7 = round 6 design with COMPILE-TIME ping-pong buffers (round 6's
// runtime-indexed kf[cur] arrays were allocated to scratch -> 2.6 GB spill
// traffic). kv-loop manually unrolled by 2; distinct named fragment sets A/B.
// K/V: global->register, disjoint per-wave slices (wave w: kv-slice 16, d-slice
// 32), prefetched one iter ahead. LDS: only P [64q][64kv] x2 buffers; one
// barrier per kv-iter. Raw-exp softmax, deferred l.
__global__ __launch_bounds__(256, 2) void flash_attn(
    const bf16* __restrict__ qn, const bf16* __restrict__ kn,
    const bf16* __restrict__ vt, bf16* __restrict__ y) {
  const int halfg = blockIdx.x >> 8;
  const int idx = blockIdx.x & 255;
  const int h = idx & 7;
  const int p = idx >> 3;
  const int qtile = halfg ? p : 63 - p;
  const int tid = threadIdx.x;
  const int wave = tid >> 6, lane = tid & 63;
  const int ln15 = lane & 15, quad = lane >> 4;
  const int ln7 = ln15 & 7;

  __shared__ __align__(16) bf16 P[2][64 * 64];  // [buf][q][8 gran], ^ (q&7)
  __shared__ float rsb[4][64];

  const int q0 = qtile * 64;
  const int nkv = qtile + 1;

  // Q B-frags for all 4 n-tiles (B[k=d][n=q]); resident all iters (64 VGPR).
  bf16x8 qf[4][4];
#pragma unroll
  for (int nf = 0; nf < 4; ++nf) {
    const bf16* qb = qn + (size_t)(q0 + nf * 16 + ln15) * 1024 + h * 128 + quad * 8;
#pragma unroll
    for (int ks = 0; ks < 4; ++ks) qf[nf][ks] = *(const bf16x8*)(qb + ks * 32);
  }

  const bf16* kbase = kn + (size_t)(wave * 16 + ln15) * 1024 + h * 128 + quad * 8;
  const bf16* vbase =
      vt + ((size_t)(h * 128 + wave * 32 + ln15)) * 4096 + quad * 8;

  bf16x8 kfA[4], kfB[4];        // A-frags: m=kv(ln15), k=d(ks*32+quad*8)
  bf16x8 vfA[2][2], vfB[2][2];  // A-frags: m=d(mf*16+ln15), k=kv(ks2*32+quad*8)

  f32x4 acc_o[2][4] = {};
  float rs[4] = {0.f, 0.f, 0.f, 0.f};

  auto loadK = [&](int kt, bf16x8 (&kf)[4]) {
    const size_t off = (size_t)(kt * 64) * 1024;
#pragma unroll
    for (int ks = 0; ks < 4; ++ks)
      kf[ks] = *(const bf16x8*)(kbase + off + ks * 32);
  };
  auto loadV = [&](int kt, bf16x8 (&vf)[2][2]) {
    const int kv0 = kt * 64;
#pragma unroll
    for (int mf = 0; mf < 2; ++mf)
#pragma unroll
      for (int ks2 = 0; ks2 < 2; ++ks2)
        vf[mf][ks2] =
            *(const bf16x8*)(vbase + (size_t)(mf * 16) * 4096 + kv0 + ks2 * 32);
  };

  // One kv-iteration; all buffer choices are compile-time via distinct refs.
  auto body = [&](int kt, bf16x8 (&kfc)[4], bf16x8 (&vfc)[2][2],
                  bf16x8 (&kfn)[4], bf16x8 (&vfn)[2][2]) {
    const int kv0 = kt * 64;
    const int ktn = (kt + 1 < nkv) ? kt + 1 : kt;  // clamped prefetch
    bf16* Pb = &P[kt & 1][0];

    // ---- phase 1: S^T[kv-slice][all q] = K-slice * Q^T
    f32x4 accs[4] = {};
#pragma unroll
    for (int ks = 0; ks < 4; ++ks)
#pragma unroll
      for (int nf = 0; nf < 4; ++nf)
        accs[nf] = __builtin_amdgcn_mfma_f32_16x16x32_bf16(
            kfc[ks], qf[nf][ks], accs[nf], 0, 0, 0);

    loadK(ktn, kfn);  // prefetch next K slice (lands during exp+phase2)

    // exp + causal mask + packed P store (4 consecutive kv at fixed q).
    const bool diag = (kt == nkv - 1);
    const int kvbase = kv0 + wave * 16 + quad * 4;
#pragma unroll
    for (int nf = 0; nf < 4; ++nf) {
      const int q = q0 + nf * 16 + ln15;
      bf16x4 pk;
#pragma unroll
      for (int r = 0; r < 4; ++r) {
        float pe = __expf(accs[nf][r]);
        if (diag && kvbase + r > q) pe = 0.f;
        rs[nf] += pe;
        pk[r] = (bf16)pe;
      }
      int gp = (wave * 2 + (quad >> 1)) ^ ln7;
      *(bf16x4*)(Pb + ((nf * 16 + ln15) * 8 + gp) * 8 + 4 * (quad & 1)) = pk;
    }
    __syncthreads();  // P complete; P-buf reuse at kt+2 gated by kt+1's barrier

    // ---- phase 2: O^T[d-slice][all q] += V^T-slice * P^T
#pragma unroll
    for (int ks2 = 0; ks2 < 2; ++ks2) {
      bf16x8 pf[4];
#pragma unroll
      for (int nf = 0; nf < 4; ++nf)
        pf[nf] = *(const bf16x8*)(
            Pb + ((nf * 16 + ln15) * 8 + ((ks2 * 4 + quad) ^ ln7)) * 8);
#pragma unroll
      for (int mf = 0; mf < 2; ++mf)
#pragma unroll
        for (int nf = 0; nf < 4; ++nf)
          acc_o[mf][nf] = __builtin_amdgcn_mfma_f32_16x16x32_bf16(
              vfc[mf][ks2], pf[nf], acc_o[mf][nf], 0, 0, 0);
    }

    loadV(ktn, vfn);  // prefetch next V slice (lands during next phase 1)
  };

  loadK(0, kfA);
  loadV(0, vfA);

  for (int kt = 0; kt < nkv; kt += 2) {
    body(kt, kfA, vfA, kfB, vfB);
    if (kt + 1 < nkv) body(kt + 1, kfB, vfB, kfA, vfA);
  }

  // l(q): reduce per-lane partials over quads, then across waves via LDS.
#pragma unroll
  for (int nf = 0; nf < 4; ++nf) {
    rs[nf] += __shfl_xor(rs[nf], 16, 64);
    rs[nf] += __shfl_xor(rs[nf], 32, 64);
  }
  if (lane < 16) {
#pragma unroll
    for (int nf = 0; nf < 4; ++nf) rsb[wave][nf * 16 + ln15] = rs[nf];
  }
  __syncthreads();
  float inv[4];
#pragma unroll
  for (int nf = 0; nf < 4; ++nf)
    inv[nf] = 1.0f / (rsb[0][nf * 16 + ln15] + rsb[1][nf * 16 + ln15] +
                      rsb[2][nf * 16 + ln15] + rsb[3][nf * 16 + ln15]);

  // O^T C-layout: d = w*32 + mf*16 + quad*4 + r, q = nf*16 + ln15.
#pragma unroll
  for (int mf = 0; mf < 2; ++mf)
#pragma unroll
    for (int nf = 0; nf < 4; ++nf) {
      bf16x4 o;
#pragma unroll
      for (int r = 0; r < 4; ++r) o[r] = (bf16)(acc_o[mf][nf][r] * inv[nf]);
      *(bf16x4*)(y + (size_t)(q0 + nf * 16 + ln15) * 1024 + h * 128 +
                 wave * 32 + mf * 16 + quad * 4) = o;
    }
}

// ---------------------------------------------------------------- launch
extern "C" void kernel_launch(void* const* d_in, const int* in_sizes, int n_in,
                              void* d_out, int out_size, void* d_ws,
                              size_t ws_size, hipStream_t stream) {
  const float* x       = (const float*)d_in[0];  // [1,4096,1024]
  const float* ve      = (const float*)d_in[1];  // [1,4096,1024]
  const float* qkv_w   = (const float*)d_in[2];  // [3,1024,1024]
  const float* lambdas = (const float*)d_in[3];  // [2]
  const float* c_proj  = (const float*)d_in[4];  // [1024,1024]
  float* out = (float*)d_out;                    // [1,4096,1024] fp32

  char* ws = (char*)d_ws;
  bf16* qkv   = (bf16*)ws;                    // 24 MiB
  bf16* xbf   = (bf16*)(ws + 25165824);       // 8 MiB
  bf16* wqkv  = (bf16*)(ws + 33554432);       // 6 MiB
  bf16* wproj = (bf16*)(ws + 39845888);       // 2 MiB
  bf16* qn    = (bf16*)(ws + 41943040);       // 8 MiB
  bf16* kn    = (bf16*)(ws + 50331648);       // 8 MiB
  bf16* vt    = (bf16*)(ws + 58720256);       // 8 MiB  [H][128][T]
  bf16* yb    = (bf16*)(ws + 67108864);       // 8 MiB

  cast3_f32_bf16<<<2048, 256, 0, stream>>>(x, xbf, 4194304 / 4, qkv_w, wqkv,
                                           3145728 / 4, c_proj, wproj,
                                           1048576 / 4);

  gemm_bt<1024, 3072, bf16><<<dim3(24, 32), 256, 0, stream>>>(xbf, wqkv, qkv);

  qkv_post<<<dim3(8, 64), 256, 0, stream>>>(qkv, ve, lambdas, qn, kn, vt);

  flash_attn<<<512, 256, 0, stream>>>(qn, kn, vt, yb);

  gemm_bt<1024, 1024, float><<<dim3(8, 32), 256, 0, stream>>>(yb, wproj, out);
}

// Round 9
// 252.305 us; speedup vs baseline: 32.5961x; 1.0349x over previous
//
#include <hip/hip_runtime.h>

typedef __bf16 bf16;
typedef __bf16 bf16x8 __attribute__((ext_vector_type(8)));
typedef __bf16 bf16x4 __attribute__((ext_vector_type(4)));
typedef __bf16 bf16x2 __attribute__((ext_vector_type(2)));
typedef float f32x4 __attribute__((ext_vector_type(4)));
typedef float f32x16 __attribute__((ext_vector_type(16)));
typedef int i32x4 __attribute__((ext_vector_type(4)));

#define GLL16(gp, lp)                                                          \
  __builtin_amdgcn_global_load_lds(                                            \
      (const __attribute__((address_space(1))) unsigned int*)(gp),             \
      (__attribute__((address_space(3))) unsigned int*)(lp), 16, 0, 0)

// ------------------------------------------------------- fused fp32->bf16 casts
__global__ __launch_bounds__(256) void cast3_f32_bf16(
    const float* __restrict__ a, bf16* __restrict__ oa, int na4,
    const float* __restrict__ b, bf16* __restrict__ ob, int nb4,
    const float* __restrict__ c, bf16* __restrict__ oc, int nc4) {
  int i = blockIdx.x * blockDim.x + threadIdx.x;
  int stride = gridDim.x * blockDim.x;
  int total = na4 + nb4 + nc4;
  for (; i < total; i += stride) {
    const float4* src;
    bf16x4* dst;
    int j = i;
    if (j < na4) {
      src = (const float4*)a + j; dst = (bf16x4*)oa + j;
    } else if ((j -= na4) < nb4) {
      src = (const float4*)b + j; dst = (bf16x4*)ob + j;
    } else {
      j -= nb4;
      src = (const float4*)c + j; dst = (bf16x4*)oc + j;
    }
    float4 v = *src;
    bf16x4 o;
    o[0] = (bf16)v.x; o[1] = (bf16)v.y; o[2] = (bf16)v.z; o[3] = (bf16)v.w;
    *dst = o;
  }
}

// ---------------------------------------------------------------- GEMM C = A * B^T
template <int K, int LDC, typename CT>
__global__ __launch_bounds__(256) void gemm_bt(
    const bf16* __restrict__ A, const bf16* __restrict__ B,
    CT* __restrict__ C) {
  __shared__ __align__(16) bf16 As[128 * 64];
  __shared__ __align__(16) bf16 Bs[128 * 64];
  const int tid  = threadIdx.x;
  const int lane = tid & 63;
  const int wave = tid >> 6;
  const int ln15 = lane & 15, quad = lane >> 4;
  const int wm = wave >> 1, wn = wave & 1;
  const int m0 = blockIdx.y * 128, n0 = blockIdx.x * 128;

  f32x4 acc[4][4] = {};

  for (int k0 = 0; k0 < K; k0 += 64) {
    __syncthreads();
#pragma unroll
    for (int j = 0; j < 4; ++j) {
      int gbase = j * 256 + wave * 64;
      int g = gbase + lane;
      int r = g >> 3, c = (g & 7) ^ (r & 7);
      GLL16(A + (size_t)(m0 + r) * K + k0 + c * 8, As + (size_t)gbase * 8);
    }
#pragma unroll
    for (int j = 0; j < 4; ++j) {
      int gbase = j * 256 + wave * 64;
      int g = gbase + lane;
      int r = g >> 3, c = (g & 7) ^ (r & 7);
      GLL16(B + (size_t)(n0 + r) * K + k0 + c * 8, Bs + (size_t)gbase * 8);
    }
    __syncthreads();
#pragma unroll
    for (int kk = 0; kk < 2; ++kk) {
      bf16x8 af[4], bfr[4];
#pragma unroll
      for (int mi = 0; mi < 4; ++mi) {
        int m = wm * 64 + mi * 16 + ln15;
        int cg = kk * 4 + quad;
        af[mi] = *(const bf16x8*)(As + (m * 8 + (cg ^ (m & 7))) * 8);
      }
#pragma unroll
      for (int ni = 0; ni < 4; ++ni) {
        int n = wn * 64 + ni * 16 + ln15;
        int cg = kk * 4 + quad;
        bfr[ni] = *(const bf16x8*)(Bs + (n * 8 + (cg ^ (n & 7))) * 8);
      }
#pragma unroll
      for (int mi = 0; mi < 4; ++mi)
#pragma unroll
        for (int ni = 0; ni < 4; ++ni)
          acc[mi][ni] = __builtin_amdgcn_mfma_f32_16x16x32_bf16(
              af[mi], bfr[ni], acc[mi][ni], 0, 0, 0);
    }
  }
#pragma unroll
  for (int mi = 0; mi < 4; ++mi)
#pragma unroll
    for (int ni = 0; ni < 4; ++ni)
#pragma unroll
      for (int r = 0; r < 4; ++r) {
        int row = m0 + wm * 64 + mi * 16 + quad * 4 + r;
        int col = n0 + wn * 64 + ni * 16 + ln15;
        C[(size_t)row * LDC + col] = (CT)acc[mi][ni][r];
      }
}

// ---------------------------------------------------------------- qkv epilogue
__global__ __launch_bounds__(256) void qkv_post(
    const bf16* __restrict__ qkv, const float* __restrict__ ve,
    const float* __restrict__ lambdas, bf16* __restrict__ qn,
    bf16* __restrict__ kn, bf16* __restrict__ vt) {
  const int h  = blockIdx.x;
  const int t0 = blockIdx.y * 64;
  const int tid = threadIdx.x;
  const int wave = tid >> 6, lane = tid & 63;
  __shared__ __align__(16) float tile[64][129];

  const int j = lane;
  float cth = 1.0f, sth = 0.0f;
  for (int i = 0; i < 16; ++i) {
    int t = t0 + wave * 16 + i;
    if (j < 32) {
      float ang = exp2f((float)j * (-10.0f / 31.0f));
      float th = (float)t * ang;
      __sincosf(th, &sth, &cth);
    }
#pragma unroll
    for (int qk = 0; qk < 2; ++qk) {
      const bf16* row = qkv + (size_t)t * 3072 + qk * 1024 + h * 128;
      float x1 = (float)row[j], x2 = (float)row[j + 64];
      float ss = x1 * x1 + x2 * x2;
#pragma unroll
      for (int m = 1; m < 64; m <<= 1) ss += __shfl_xor(ss, m, 64);
      float rinv = rsqrtf(ss * (1.0f / 128.0f) + 1.1920929e-7f);
      if (qk == 0) rinv *= 0.12f;  // fold ATTN_SCALE into q
      float y1 = (x1 * cth + x2 * sth) * rinv;
      float y2 = (x2 * cth - x1 * sth) * rinv;
      bf16* orow = (qk == 0 ? qn : kn) + (size_t)t * 1024 + h * 128;
      orow[j] = (bf16)y1;
      orow[j + 64] = (bf16)y2;
    }
  }

  float l0 = lambdas[0], l1 = lambdas[1];
  for (int c = 0; c < 32; ++c) {
    int idx = c * 256 + tid;
    int d = idx & 127, tl = idx >> 7;
    int t = t0 + tl;
    float v = (float)qkv[(size_t)t * 3072 + 2048 + h * 128 + d];
    float vev = ve[(size_t)t * 1024 + h * 128 + d];
    tile[tl][d] = l0 * v + l1 * vev;
  }
  __syncthreads();
  for (int c = 0; c < 32; ++c) {
    int idx = c * 256 + tid;
    int tl = idx & 63, d = idx >> 6;
    vt[((size_t)(h * 128 + d)) * 4096 + t0 + tl] = (bf16)tile[tl][d];
  }
}

// ---------------------------------------------------------------- flash attention
// Round 9 = round 8 with the phase-2 V granule FIX: wave (qi,ki) pairs its P
// (kv = 32*ki + 16c + 8hl + j) with V granule 4*ki + 2c + hl (round 8 omitted
// the 4*ki term, so ki=1 waves used V columns 0..31 — the correctness bug).
// 32x32x16 MFMA + in-register P transpose (shfl_xor 32 + selects); no P LDS,
// no mid-loop barrier. K/V GLL16 double-buffered, ONE barrier per kv-iter.
// Raw-exp softmax; kv-half O partials combined once in the epilogue via LDS.
__global__ __launch_bounds__(256, 2) void flash_attn(
    const bf16* __restrict__ qn, const bf16* __restrict__ kn,
    const bf16* __restrict__ vt, bf16* __restrict__ y) {
  const int halfg = blockIdx.x >> 8;
  const int idx = blockIdx.x & 255;
  const int h = idx & 7;
  const int p = idx >> 3;
  const int qtile = halfg ? p : 63 - p;
  const int tid = threadIdx.x;
  const int wave = tid >> 6, lane = tid & 63;
  const int l31 = lane & 31, hl = lane >> 5;
  const int qi = wave >> 1, ki = wave & 1;

  __shared__ __align__(16) bf16 Ks[2][64 * 128];  // [buf][kv][16 gran] ^(kv&15)
  __shared__ __align__(16) bf16 Vs[2][128 * 64];  // [buf][d][8 gran]  ^(d&7)
  __shared__ float rsb[2][2][32];                  // [qi][ki][q]

  const int q0 = qtile * 64;
  const int nkv = qtile + 1;
  const int qg = q0 + qi * 32 + l31;  // this lane's q (B n-dim / C col)

  // Q B-frags (B[k=d][n=q], k=(lane>>5)*8+j): 8 frags cover d=0..127.
  bf16x8 qf[8];
  {
    const bf16* qb = qn + (size_t)qg * 1024 + h * 128 + hl * 8;
#pragma unroll
    for (int f = 0; f < 8; ++f) qf[f] = *(const bf16x8*)(qb + f * 16);
  }

  f32x16 acc_o[4] = {};  // O^T[d=dt*32+..][q 32] for this (qi,ki)
  float rs = 0.0f;

  auto prefetch = [&](int kt, int buf) {
    const int kv0 = kt * 64;
    bf16* ks = &Ks[buf][0];
    bf16* vs = &Vs[buf][0];
#pragma unroll
    for (int jj = 0; jj < 4; ++jj) {  // K tile: 64 rows x 16 granules
      int gbase = jj * 256 + wave * 64;
      int g = gbase + lane;
      int r = g >> 4, c = (g & 15) ^ (r & 15);
      GLL16(kn + (size_t)(kv0 + r) * 1024 + h * 128 + c * 8,
            ks + (size_t)gbase * 8);
    }
#pragma unroll
    for (int jj = 0; jj < 4; ++jj) {  // V^T tile: 128 rows x 8 granules
      int gbase = jj * 256 + wave * 64;
      int g = gbase + lane;
      int d = g >> 3, c = (g & 7) ^ (d & 7);
      GLL16(vt + ((size_t)(h * 128 + d)) * 4096 + kv0 + c * 8,
            vs + (size_t)gbase * 8);
    }
  };

  prefetch(0, 0);

  for (int kt = 0; kt < nkv; ++kt) {
    const int kv0 = kt * 64;
    __syncthreads();  // drains this wave's GLL16s; gates buffer reuse
    if (kt + 1 < nkv) prefetch(kt + 1, (kt + 1) & 1);
    const bf16* ksb = &Ks[kt & 1][0];
    const bf16* vsb = &Vs[kt & 1][0];

    // ---- S^T[kv-half ki][q-half qi] = K-slice * Q^T (8 chained 32x32x16)
    f32x16 accs = {};
    const int krow = ki * 32 + l31;
#pragma unroll
    for (int f = 0; f < 8; ++f) {
      bf16x8 a =
          *(const bf16x8*)(ksb + (krow * 16 + ((2 * f + hl) ^ (krow & 15))) * 8);
      accs = __builtin_amdgcn_mfma_f32_32x32x16_bf16(a, qf[f], accs, 0, 0, 0);
    }

    // ---- exp + causal mask (C row = (r&3)+8*(r>>2)+4*hl)
    const bool diag = (kt == nkv - 1);
    float pe[16];
#pragma unroll
    for (int r = 0; r < 16; ++r) {
      int kvl = (r & 3) + 8 * (r >> 2) + 4 * hl;
      float v = __expf(accs[r]);
      if (diag && (kv0 + ki * 32 + kvl) > qg) v = 0.0f;
      rs += v;
      pe[r] = v;
    }
    // pack kv-pairs: pk[g] = (kv base(g)+4hl, +1), base(g)=8*(g>>1)+2*(g&1)
    int pk[8];
#pragma unroll
    for (int g = 0; g < 8; ++g) {
      bf16x2 t;
      t[0] = (bf16)pe[2 * g];
      t[1] = (bf16)pe[2 * g + 1];
      pk[g] = __builtin_bit_cast(int, t);
    }

    // ---- in-register transpose to PV B-frags (k=kv chunk c: kv 16c+8hl+j,
    //      local to this wave's kv-half)
    bf16x8 pf[2];
#pragma unroll
    for (int c = 0; c < 2; ++c) {
      int sh0 = __shfl_xor(pk[4 * c + 0], 32, 64);
      int sh1 = __shfl_xor(pk[4 * c + 1], 32, 64);
      int sh2 = __shfl_xor(pk[4 * c + 2], 32, 64);
      int sh3 = __shfl_xor(pk[4 * c + 3], 32, 64);
      int own0 = hl ? pk[4 * c + 2] : pk[4 * c + 0];
      int own1 = hl ? pk[4 * c + 3] : pk[4 * c + 1];
      int par0 = hl ? sh2 : sh0;
      int par1 = hl ? sh3 : sh1;
      i32x4 dv;
      dv[0] = hl ? par0 : own0;  // t=0: src half 0
      dv[1] = hl ? par1 : own1;  // t=1: src half 0
      dv[2] = hl ? own0 : par0;  // t=2: src half 1
      dv[3] = hl ? own1 : par1;  // t=3: src half 1
      pf[c] = __builtin_bit_cast(bf16x8, dv);
    }

    // ---- O^T[d][q-half] += V^T-slice * P^T (4 d-tiles x 2 kv-chunks)
    //      V kv-granule = 4*ki + 2*c + hl  (matches this wave's kv-half!)
#pragma unroll
    for (int dt = 0; dt < 4; ++dt) {
      int vrow = dt * 32 + l31;
#pragma unroll
      for (int c = 0; c < 2; ++c) {
        bf16x8 a = *(const bf16x8*)(
            vsb + (vrow * 8 + ((4 * ki + 2 * c + hl) ^ (vrow & 7))) * 8);
        acc_o[dt] =
            __builtin_amdgcn_mfma_f32_32x32x16_bf16(a, pf[c], acc_o[dt], 0, 0, 0);
      }
    }
  }

  // ---- epilogue: combine kv-halves via LDS (reuse Ks), normalize, store.
  rs += __shfl_xor(rs, 32, 64);
  __syncthreads();  // all waves done reading K/V LDS
  if (lane < 32) rsb[qi][ki][l31] = rs;
  float* ob = (float*)&Ks[0][0];  // 2 x 16 KB f32 regions (one per qi)
  if (ki == 1) {
#pragma unroll
    for (int dt = 0; dt < 4; ++dt)
#pragma unroll
      for (int r = 0; r < 16; ++r) {
        int d = dt * 32 + (r & 3) + 8 * (r >> 2) + 4 * hl;
        ob[qi * 4096 + l31 * 128 + d] = acc_o[dt][r];
      }
  }
  __syncthreads();
  if (ki == 0) {
    float inv = 1.0f / (rsb[qi][0][l31] + rsb[qi][1][l31]);
#pragma unroll
    for (int dt = 0; dt < 4; ++dt)
#pragma unroll
      for (int rg = 0; rg < 4; ++rg) {
        bf16x4 o;
#pragma unroll
        for (int j = 0; j < 4; ++j) {
          int r = rg * 4 + j;
          int d = dt * 32 + 4 * hl + 8 * rg + j;
          o[j] = (bf16)((acc_o[dt][r] + ob[qi * 4096 + l31 * 128 + d]) * inv);
        }
        *(bf16x4*)(y + (size_t)qg * 1024 + h * 128 + dt * 32 + 4 * hl + 8 * rg) = o;
      }
  }
}

// ---------------------------------------------------------------- launch
extern "C" void kernel_launch(void* const* d_in, const int* in_sizes, int n_in,
                              void* d_out, int out_size, void* d_ws,
                              size_t ws_size, hipStream_t stream) {
  const float* x       = (const float*)d_in[0];  // [1,4096,1024]
  const float* ve      = (const float*)d_in[1];  // [1,4096,1024]
  const float* qkv_w   = (const float*)d_in[2];  // [3,1024,1024]
  const float* lambdas = (const float*)d_in[3];  // [2]
  const float* c_proj  = (const float*)d_in[4];  // [1024,1024]
  float* out = (float*)d_out;                    // [1,4096,1024] fp32

  char* ws = (char*)d_ws;
  bf16* qkv   = (bf16*)ws;                    // 24 MiB
  bf16* xbf   = (bf16*)(ws + 25165824);       // 8 MiB
  bf16* wqkv  = (bf16*)(ws + 33554432);       // 6 MiB
  bf16* wproj = (bf16*)(ws + 39845888);       // 2 MiB
  bf16* qn    = (bf16*)(ws + 41943040);       // 8 MiB
  bf16* kn    = (bf16*)(ws + 50331648);       // 8 MiB
  bf16* vt    = (bf16*)(ws + 58720256);       // 8 MiB  [H][128][T]
  bf16* yb    = (bf16*)(ws + 67108864);       // 8 MiB

  cast3_f32_bf16<<<2048, 256, 0, stream>>>(x, xbf, 4194304 / 4, qkv_w, wqkv,
                                           3145728 / 4, c_proj, wproj,
                                           1048576 / 4);

  gemm_bt<1024, 3072, bf16><<<dim3(24, 32), 256, 0, stream>>>(xbf, wqkv, qkv);

  qkv_post<<<dim3(8, 64), 256, 0, stream>>>(qkv, ve, lambdas, qn, kn, vt);

  flash_attn<<<512, 256, 0, stream>>>(qn, kn, vt, yb);

  gemm_bt<1024, 1024, float><<<dim3(8, 32), 256, 0, stream>>>(yb, wproj, out);
}

// Round 10
// 241.160 us; speedup vs baseline: 34.1026x; 1.0462x over previous
//
#include <hip/hip_runtime.h>

typedef __bf16 bf16;
typedef __bf16 bf16x8 __attribute__((ext_vector_type(8)));
typedef __bf16 bf16x4 __attribute__((ext_vector_type(4)));
typedef __bf16 bf16x2 __attribute__((ext_vector_type(2)));
typedef float f32x4 __attribute__((ext_vector_type(4)));
typedef float f32x16 __attribute__((ext_vector_type(16)));
typedef int i32x4 __attribute__((ext_vector_type(4)));

#define GLL16(gp, lp)                                                          \
  __builtin_amdgcn_global_load_lds(                                            \
      (const __attribute__((address_space(1))) unsigned int*)(gp),             \
      (__attribute__((address_space(3))) unsigned int*)(lp), 16, 0, 0)

// ------------------------------------------------------- fused fp32->bf16 casts
__global__ __launch_bounds__(256) void cast3_f32_bf16(
    const float* __restrict__ a, bf16* __restrict__ oa, int na4,
    const float* __restrict__ b, bf16* __restrict__ ob, int nb4,
    const float* __restrict__ c, bf16* __restrict__ oc, int nc4) {
  int i = blockIdx.x * blockDim.x + threadIdx.x;
  int stride = gridDim.x * blockDim.x;
  int total = na4 + nb4 + nc4;
  for (; i < total; i += stride) {
    const float4* src;
    bf16x4* dst;
    int j = i;
    if (j < na4) {
      src = (const float4*)a + j; dst = (bf16x4*)oa + j;
    } else if ((j -= na4) < nb4) {
      src = (const float4*)b + j; dst = (bf16x4*)ob + j;
    } else {
      j -= nb4;
      src = (const float4*)c + j; dst = (bf16x4*)oc + j;
    }
    float4 v = *src;
    bf16x4 o;
    o[0] = (bf16)v.x; o[1] = (bf16)v.y; o[2] = (bf16)v.z; o[3] = (bf16)v.w;
    *dst = o;
  }
}

// ---------------------------------------------------------------- GEMM C = A * B^T
template <int K, int LDC, typename CT>
__global__ __launch_bounds__(256) void gemm_bt(
    const bf16* __restrict__ A, const bf16* __restrict__ B,
    CT* __restrict__ C) {
  __shared__ __align__(16) bf16 As[128 * 64];
  __shared__ __align__(16) bf16 Bs[128 * 64];
  const int tid  = threadIdx.x;
  const int lane = tid & 63;
  const int wave = tid >> 6;
  const int ln15 = lane & 15, quad = lane >> 4;
  const int wm = wave >> 1, wn = wave & 1;
  const int m0 = blockIdx.y * 128, n0 = blockIdx.x * 128;

  f32x4 acc[4][4] = {};

  for (int k0 = 0; k0 < K; k0 += 64) {
    __syncthreads();
#pragma unroll
    for (int j = 0; j < 4; ++j) {
      int gbase = j * 256 + wave * 64;
      int g = gbase + lane;
      int r = g >> 3, c = (g & 7) ^ (r & 7);
      GLL16(A + (size_t)(m0 + r) * K + k0 + c * 8, As + (size_t)gbase * 8);
    }
#pragma unroll
    for (int j = 0; j < 4; ++j) {
      int gbase = j * 256 + wave * 64;
      int g = gbase + lane;
      int r = g >> 3, c = (g & 7) ^ (r & 7);
      GLL16(B + (size_t)(n0 + r) * K + k0 + c * 8, Bs + (size_t)gbase * 8);
    }
    __syncthreads();
#pragma unroll
    for (int kk = 0; kk < 2; ++kk) {
      bf16x8 af[4], bfr[4];
#pragma unroll
      for (int mi = 0; mi < 4; ++mi) {
        int m = wm * 64 + mi * 16 + ln15;
        int cg = kk * 4 + quad;
        af[mi] = *(const bf16x8*)(As + (m * 8 + (cg ^ (m & 7))) * 8);
      }
#pragma unroll
      for (int ni = 0; ni < 4; ++ni) {
        int n = wn * 64 + ni * 16 + ln15;
        int cg = kk * 4 + quad;
        bfr[ni] = *(const bf16x8*)(Bs + (n * 8 + (cg ^ (n & 7))) * 8);
      }
#pragma unroll
      for (int mi = 0; mi < 4; ++mi)
#pragma unroll
        for (int ni = 0; ni < 4; ++ni)
          acc[mi][ni] = __builtin_amdgcn_mfma_f32_16x16x32_bf16(
              af[mi], bfr[ni], acc[mi][ni], 0, 0, 0);
    }
  }
#pragma unroll
  for (int mi = 0; mi < 4; ++mi)
#pragma unroll
    for (int ni = 0; ni < 4; ++ni)
#pragma unroll
      for (int r = 0; r < 4; ++r) {
        int row = m0 + wm * 64 + mi * 16 + quad * 4 + r;
        int col = n0 + wn * 64 + ni * 16 + ln15;
        C[(size_t)row * LDC + col] = (CT)acc[mi][ni][r];
      }
}

// ---------------------------------------------------------------- qkv epilogue
__global__ __launch_bounds__(256) void qkv_post(
    const bf16* __restrict__ qkv, const float* __restrict__ ve,
    const float* __restrict__ lambdas, bf16* __restrict__ qn,
    bf16* __restrict__ kn, bf16* __restrict__ vt) {
  const int h  = blockIdx.x;
  const int t0 = blockIdx.y * 64;
  const int tid = threadIdx.x;
  const int wave = tid >> 6, lane = tid & 63;
  __shared__ __align__(16) float tile[64][129];

  const int j = lane;
  float cth = 1.0f, sth = 0.0f;
  for (int i = 0; i < 16; ++i) {
    int t = t0 + wave * 16 + i;
    if (j < 32) {
      float ang = exp2f((float)j * (-10.0f / 31.0f));
      float th = (float)t * ang;
      __sincosf(th, &sth, &cth);
    }
#pragma unroll
    for (int qk = 0; qk < 2; ++qk) {
      const bf16* row = qkv + (size_t)t * 3072 + qk * 1024 + h * 128;
      float x1 = (float)row[j], x2 = (float)row[j + 64];
      float ss = x1 * x1 + x2 * x2;
#pragma unroll
      for (int m = 1; m < 64; m <<= 1) ss += __shfl_xor(ss, m, 64);
      float rinv = rsqrtf(ss * (1.0f / 128.0f) + 1.1920929e-7f);
      if (qk == 0) rinv *= 0.12f;  // fold ATTN_SCALE into q
      float y1 = (x1 * cth + x2 * sth) * rinv;
      float y2 = (x2 * cth - x1 * sth) * rinv;
      bf16* orow = (qk == 0 ? qn : kn) + (size_t)t * 1024 + h * 128;
      orow[j] = (bf16)y1;
      orow[j + 64] = (bf16)y2;
    }
  }

  float l0 = lambdas[0], l1 = lambdas[1];
  for (int c = 0; c < 32; ++c) {
    int idx = c * 256 + tid;
    int d = idx & 127, tl = idx >> 7;
    int t = t0 + tl;
    float v = (float)qkv[(size_t)t * 3072 + 2048 + h * 128 + d];
    float vev = ve[(size_t)t * 1024 + h * 128 + d];
    tile[tl][d] = l0 * v + l1 * vev;
  }
  __syncthreads();
  for (int c = 0; c < 32; ++c) {
    int idx = c * 256 + tid;
    int tl = idx & 63, d = idx >> 6;
    vt[((size_t)(h * 128 + d)) * 4096 + t0 + tl] = (bf16)tile[tl][d];
  }
}

// ---------------------------------------------------------------- flash attention
// Round 10: kv-SPLIT balanced grid. 1024 blocks = (h, qtile, kv-half); block
// work = ~nkv/2 in [0..32] iters; qtile-descending dispatch => near-perfect
// CU packing (2 busy blocks/CU for the whole run vs round-9's effective 1).
// Each block writes RAW partial O (f32) + partial l; attn_combine merges.
// Compute core = round 9 (32x32x16, in-register P transpose, 1 barrier/iter).
// Epilogue LDS pad 128->129 kills the 32-way bank conflicts.
__global__ __launch_bounds__(256, 2) void flash_attn(
    const bf16* __restrict__ qn, const bf16* __restrict__ kn,
    const bf16* __restrict__ vt, float* __restrict__ Op,
    float* __restrict__ ls) {
  const int id = blockIdx.x;            // 0..1023
  const int qtile = 63 - (id >> 4);     // long blocks first
  const int sub = id & 15;
  const int h = sub >> 1;
  const int half = sub & 1;
  const int tid = threadIdx.x;
  const int wave = tid >> 6, lane = tid & 63;
  const int l31 = lane & 31, hl = lane >> 5;
  const int qi = wave >> 1, ki = wave & 1;

  __shared__ __align__(16) bf16 smem[4 * 64 * 128];  // 64 KB: Ks(2x16K)+Vs(2x16K)
  __shared__ float rsb[2][2][32];                    // [qi][ki][q]
  bf16* Ks = smem;                  // [buf][kv][16 gran] ^(kv&15)
  bf16* Vs = smem + 2 * 64 * 128;   // [buf][d][8 gran]  ^(d&7)

  const int q0 = qtile * 64;
  const int nkv = qtile + 1;
  const int half0 = (nkv + 1) >> 1;
  const int kt_begin = half ? half0 : 0;
  const int kt_end = half ? nkv : half0;
  const int niter = kt_end - kt_begin;
  const int pidx = (h * 64 + qtile) * 2 + half;

  if (niter == 0) {  // qtile 0, half 1: zero partials
    float4 z = {0.f, 0.f, 0.f, 0.f};
    float* opb = Op + (size_t)pidx * 8192;
#pragma unroll
    for (int j = 0; j < 8; ++j) *(float4*)(opb + tid * 32 + j * 4) = z;
    if (tid < 64) ls[pidx * 64 + tid] = 0.f;
    return;
  }

  const int qg = q0 + qi * 32 + l31;  // this lane's q (B n-dim / C col)

  // Q B-frags (B[k=d][n=q], k=(lane>>5)*8+j): 8 frags cover d=0..127.
  bf16x8 qf[8];
  {
    const bf16* qb = qn + (size_t)qg * 1024 + h * 128 + hl * 8;
#pragma unroll
    for (int f = 0; f < 8; ++f) qf[f] = *(const bf16x8*)(qb + f * 16);
  }

  f32x16 acc_o[4] = {};  // O^T[d=dt*32+..][q 32] for this (qi,ki)
  float rs = 0.0f;

  auto prefetch = [&](int kt, int buf) {
    const int kv0 = kt * 64;
    bf16* ks = Ks + buf * (64 * 128);
    bf16* vs = Vs + buf * (128 * 64);
#pragma unroll
    for (int jj = 0; jj < 4; ++jj) {  // K tile: 64 rows x 16 granules
      int gbase = jj * 256 + wave * 64;
      int g = gbase + lane;
      int r = g >> 4, c = (g & 15) ^ (r & 15);
      GLL16(kn + (size_t)(kv0 + r) * 1024 + h * 128 + c * 8,
            ks + (size_t)gbase * 8);
    }
#pragma unroll
    for (int jj = 0; jj < 4; ++jj) {  // V^T tile: 128 rows x 8 granules
      int gbase = jj * 256 + wave * 64;
      int g = gbase + lane;
      int d = g >> 3, c = (g & 7) ^ (d & 7);
      GLL16(vt + ((size_t)(h * 128 + d)) * 4096 + kv0 + c * 8,
            vs + (size_t)gbase * 8);
    }
  };

  prefetch(kt_begin, 0);

  for (int it = 0; it < niter; ++it) {
    const int kt = kt_begin + it;
    const int kv0 = kt * 64;
    __syncthreads();  // drains this wave's GLL16s; gates buffer reuse
    if (it + 1 < niter) prefetch(kt + 1, (it + 1) & 1);
    const bf16* ksb = Ks + (it & 1) * (64 * 128);
    const bf16* vsb = Vs + (it & 1) * (128 * 64);

    // ---- S^T[kv-half ki][q-half qi] = K-slice * Q^T (8 chained 32x32x16)
    f32x16 accs = {};
    const int krow = ki * 32 + l31;
#pragma unroll
    for (int f = 0; f < 8; ++f) {
      bf16x8 a =
          *(const bf16x8*)(ksb + (krow * 16 + ((2 * f + hl) ^ (krow & 15))) * 8);
      accs = __builtin_amdgcn_mfma_f32_32x32x16_bf16(a, qf[f], accs, 0, 0, 0);
    }

    // ---- exp + causal mask (C row = (r&3)+8*(r>>2)+4*hl)
    const bool diag = (kt == nkv - 1);
    float pe[16];
#pragma unroll
    for (int r = 0; r < 16; ++r) {
      int kvl = (r & 3) + 8 * (r >> 2) + 4 * hl;
      float v = __expf(accs[r]);
      if (diag && (kv0 + ki * 32 + kvl) > qg) v = 0.0f;
      rs += v;
      pe[r] = v;
    }
    // pack kv-pairs: pk[g] = (kv base(g)+4hl, +1), base(g)=8*(g>>1)+2*(g&1)
    int pk[8];
#pragma unroll
    for (int g = 0; g < 8; ++g) {
      bf16x2 t;
      t[0] = (bf16)pe[2 * g];
      t[1] = (bf16)pe[2 * g + 1];
      pk[g] = __builtin_bit_cast(int, t);
    }

    // ---- in-register transpose to PV B-frags (k=kv chunk c, wave-local half)
    bf16x8 pf[2];
#pragma unroll
    for (int c = 0; c < 2; ++c) {
      int sh0 = __shfl_xor(pk[4 * c + 0], 32, 64);
      int sh1 = __shfl_xor(pk[4 * c + 1], 32, 64);
      int sh2 = __shfl_xor(pk[4 * c + 2], 32, 64);
      int sh3 = __shfl_xor(pk[4 * c + 3], 32, 64);
      int own0 = hl ? pk[4 * c + 2] : pk[4 * c + 0];
      int own1 = hl ? pk[4 * c + 3] : pk[4 * c + 1];
      int par0 = hl ? sh2 : sh0;
      int par1 = hl ? sh3 : sh1;
      i32x4 dv;
      dv[0] = hl ? par0 : own0;  // t=0: src half 0
      dv[1] = hl ? par1 : own1;  // t=1: src half 0
      dv[2] = hl ? own0 : par0;  // t=2: src half 1
      dv[3] = hl ? own1 : par1;  // t=3: src half 1
      pf[c] = __builtin_bit_cast(bf16x8, dv);
    }

    // ---- O^T[d][q-half] += V^T-slice * P^T; V kv-granule = 4*ki + 2*c + hl
#pragma unroll
    for (int dt = 0; dt < 4; ++dt) {
      int vrow = dt * 32 + l31;
#pragma unroll
      for (int c = 0; c < 2; ++c) {
        bf16x8 a = *(const bf16x8*)(
            vsb + (vrow * 8 + ((4 * ki + 2 * c + hl) ^ (vrow & 7))) * 8);
        acc_o[dt] =
            __builtin_amdgcn_mfma_f32_32x32x16_bf16(a, pf[c], acc_o[dt], 0, 0, 0);
      }
    }
  }

  // ---- epilogue: combine ki-halves via LDS (pad 129 -> conflict-free),
  //      write RAW partial O (f32) + partial l for attn_combine.
  rs += __shfl_xor(rs, 32, 64);
  __syncthreads();  // all waves done reading K/V LDS
  if (lane < 32) rsb[qi][ki][l31] = rs;
  float* ob = (float*)smem;  // [64 q][129] f32 = 33 KB
  if (ki == 1) {
#pragma unroll
    for (int dt = 0; dt < 4; ++dt)
#pragma unroll
      for (int r = 0; r < 16; ++r) {
        int d = dt * 32 + (r & 3) + 8 * (r >> 2) + 4 * hl;
        ob[(qi * 32 + l31) * 129 + d] = acc_o[dt][r];
      }
  }
  __syncthreads();
  if (ki == 0) {
    float lsum = rsb[qi][0][l31] + rsb[qi][1][l31];
    if (hl == 0) ls[pidx * 64 + qi * 32 + l31] = lsum;
    float* opb = Op + (size_t)pidx * 8192 + (qi * 32 + l31) * 128;
#pragma unroll
    for (int dt = 0; dt < 4; ++dt)
#pragma unroll
      for (int rg = 0; rg < 4; ++rg) {
        float4 o;
        int d0 = dt * 32 + 4 * hl + 8 * rg;
        o.x = acc_o[dt][rg * 4 + 0] + ob[(qi * 32 + l31) * 129 + d0 + 0];
        o.y = acc_o[dt][rg * 4 + 1] + ob[(qi * 32 + l31) * 129 + d0 + 1];
        o.z = acc_o[dt][rg * 4 + 2] + ob[(qi * 32 + l31) * 129 + d0 + 2];
        o.w = acc_o[dt][rg * 4 + 3] + ob[(qi * 32 + l31) * 129 + d0 + 3];
        *(float4*)(opb + d0) = o;
      }
  }
}

// ---------------------------------------------------------------- combine halves
// y[t][h*128+d] = (Op[h,qtile,0] + Op[h,qtile,1]) / (l0 + l1), bf16.
__global__ __launch_bounds__(256) void attn_combine(
    const float* __restrict__ Op, const float* __restrict__ ls,
    bf16* __restrict__ y) {
  int gid = blockIdx.x * 256 + threadIdx.x;  // one float4 of output each
  int t = gid >> 8;
  int c4 = gid & 255;
  int qtile = t >> 6, ql = t & 63;
  int h = c4 >> 5;
  int d = (c4 & 31) * 4;
  int pbase = (h * 64 + qtile) * 2;
  const float4 o0 = *(const float4*)(Op + (size_t)pbase * 8192 + ql * 128 + d);
  const float4 o1 =
      *(const float4*)(Op + (size_t)(pbase + 1) * 8192 + ql * 128 + d);
  float inv = 1.0f / (ls[pbase * 64 + ql] + ls[(pbase + 1) * 64 + ql]);
  bf16x4 o;
  o[0] = (bf16)((o0.x + o1.x) * inv);
  o[1] = (bf16)((o0.y + o1.y) * inv);
  o[2] = (bf16)((o0.z + o1.z) * inv);
  o[3] = (bf16)((o0.w + o1.w) * inv);
  *(bf16x4*)(y + (size_t)t * 1024 + h * 128 + d) = o;
}

// ---------------------------------------------------------------- launch
extern "C" void kernel_launch(void* const* d_in, const int* in_sizes, int n_in,
                              void* d_out, int out_size, void* d_ws,
                              size_t ws_size, hipStream_t stream) {
  const float* x       = (const float*)d_in[0];  // [1,4096,1024]
  const float* ve      = (const float*)d_in[1];  // [1,4096,1024]
  const float* qkv_w   = (const float*)d_in[2];  // [3,1024,1024]
  const float* lambdas = (const float*)d_in[3];  // [2]
  const float* c_proj  = (const float*)d_in[4];  // [1024,1024]
  float* out = (float*)d_out;                    // [1,4096,1024] fp32

  char* ws = (char*)d_ws;
  bf16* qkv   = (bf16*)ws;                    // 24 MiB (dead after qkv_post)
  bf16* xbf   = (bf16*)(ws + 25165824);       // 8 MiB  (dead after gemm1)
  bf16* wqkv  = (bf16*)(ws + 33554432);       // 6 MiB  (dead after gemm1)
  bf16* wproj = (bf16*)(ws + 39845888);       // 2 MiB
  bf16* qn    = (bf16*)(ws + 41943040);       // 8 MiB
  bf16* kn    = (bf16*)(ws + 50331648);       // 8 MiB
  bf16* vt    = (bf16*)(ws + 58720256);       // 8 MiB  [H][128][T]
  bf16* yb    = (bf16*)(ws + 67108864);       // 8 MiB
  // flash partials ALIAS dead regions (stream-ordered: flash runs after
  // gemm1/qkv_post consumed them):
  float* Op  = (float*)ws;                    // 32 MiB  [1024][64][128] f32
  float* lsw = (float*)(ws + 33554432);       // 256 KiB [1024][64] f32

  cast3_f32_bf16<<<2048, 256, 0, stream>>>(x, xbf, 4194304 / 4, qkv_w, wqkv,
                                           3145728 / 4, c_proj, wproj,
                                           1048576 / 4);

  gemm_bt<1024, 3072, bf16><<<dim3(24, 32), 256, 0, stream>>>(xbf, wqkv, qkv);

  qkv_post<<<dim3(8, 64), 256, 0, stream>>>(qkv, ve, lambdas, qn, kn, vt);

  flash_attn<<<1024, 256, 0, stream>>>(qn, kn, vt, Op, lsw);
  attn_combine<<<4096, 256, 0, stream>>>(Op, lsw, yb);

  gemm_bt<1024, 1024, float><<<dim3(8, 32), 256, 0, stream>>>(yb, wproj, out);
}